// Round 10
// baseline (455.869 us; speedup 1.0000x reference)
//
#include <hip/hip_runtime.h>
#include <hip/hip_bf16.h>

#define N_NODES 50000
#define N_EDGES 1600000
#define N_GRAPHS 64
#define D_IN 128
#define D_H 512
#define D_OUT 16

// atomic-free CSR build: buckets of 256 rows
#define NBUK 196                      // ceil(50000/256)
#define BUK_CAP 9216                  // per-bucket capacity: mean 8192 + ~11 sigma
#define P1_EDGES 8192                 // edges per partition block
#define P1_BLOCKS ((N_EDGES + P1_EDGES - 1) / P1_EDGES)   // 196

#define CHUNK_U 16                    // 16 u32 = 32 bf16 features = 64 B per chunk-row
#define NCHUNK 4

typedef short bf16x8 __attribute__((ext_vector_type(8)));
typedef float f32x4 __attribute__((ext_vector_type(4)));

static __device__ __forceinline__ unsigned short f2bf(float f) {
    __hip_bfloat16 h = __float2bfloat16(f);   // RNE
    return *(unsigned short*)&h;
}

// batch is SORTED: gcnt[g] = lower_bound(g+1) - lower_bound(g). 64 threads, no atomics.
__global__ __launch_bounds__(64) void graph_counts(const int* __restrict__ batch,
                                                   int* __restrict__ gcnt) {
    int g = threadIdx.x;
    int lo = 0, hi = N_NODES;
    while (lo < hi) { int mid = (lo + hi) >> 1; if (batch[mid] < g) lo = mid + 1; else hi = mid; }
    int a = lo;
    lo = 0; hi = N_NODES;
    while (lo < hi) { int mid = (lo + hi) >> 1; if (batch[mid] < g + 1) lo = mid + 1; else hi = mid; }
    gcnt[g] = lo - a;
}

// ---------------------------------------------------------------- CSR build (atomic-free)

__global__ __launch_bounds__(256) void partition_edges(const int* __restrict__ row,
                                                       const int* __restrict__ col,
                                                       int* __restrict__ bucket_cnt,
                                                       unsigned* __restrict__ edge_buf) {
    __shared__ unsigned recs[P1_EDGES];     // 32 KB
    __shared__ unsigned sorted[P1_EDGES];   // 32 KB
    __shared__ int hist[NBUK];              // counts, then repurposed as local excl base
    __shared__ int cur[NBUK];
    __shared__ int gbase[NBUK];
    __shared__ int scan[256];
    int tid = threadIdx.x;
    int e0 = blockIdx.x * P1_EDGES;
    int m = N_EDGES - e0; if (m > P1_EDGES) m = P1_EDGES;

    for (int i = tid; i < NBUK; i += 256) { hist[i] = 0; cur[i] = 0; }
    __syncthreads();
    for (int i = tid; i < m; i += 256) {
        int r = row[e0 + i];
        int c = col[e0 + i];
        int buk = r >> 8;
        recs[i] = ((unsigned)buk << 24) | ((unsigned)(r & 255) << 16) | (unsigned)c;
        atomicAdd(&hist[buk], 1);
    }
    __syncthreads();
    scan[tid] = (tid < NBUK) ? hist[tid] : 0;
    __syncthreads();
    for (int off = 1; off < 256; off <<= 1) {
        int v = (tid >= off) ? scan[tid - off] : 0;
        __syncthreads();
        scan[tid] += v;
        __syncthreads();
    }
    if (tid < NBUK) {
        int cnt = hist[tid];
        hist[tid] = (tid == 0) ? 0 : scan[tid - 1];            // local excl base
        gbase[tid] = (cnt > 0) ? atomicAdd(&bucket_cnt[tid], cnt) : 0;  // reserve range
    }
    __syncthreads();
    for (int i = tid; i < m; i += 256) {                       // rank + reorder (bucket-major)
        unsigned rec = recs[i];
        int buk = rec >> 24;
        int rank = atomicAdd(&cur[buk], 1);
        sorted[hist[buk] + rank] = rec;
    }
    __syncthreads();
    for (int p = tid; p < m; p += 256) {                       // coalesced-run writes
        unsigned rec = sorted[p];
        int buk = rec >> 24;
        edge_buf[(size_t)buk * BUK_CAP + gbase[buk] + (p - hist[buk])] = rec;
    }
}

__global__ __launch_bounds__(256) void scan_buckets(const int* __restrict__ bucket_cnt,
                                                    int* __restrict__ bucket_base) {
    __shared__ int scan[256];
    int tid = threadIdx.x;
    scan[tid] = (tid < NBUK) ? bucket_cnt[tid] : 0;
    __syncthreads();
    for (int off = 1; off < 256; off <<= 1) {
        int v = (tid >= off) ? scan[tid - off] : 0;
        __syncthreads();
        scan[tid] += v;
        __syncthreads();
    }
    if (tid < NBUK) bucket_base[tid] = (tid == 0) ? 0 : scan[tid - 1];
}

// P2: one block per bucket. LDS hist+scan -> rowptr/invdeg; LDS-cursor scatter into the
// bucket's contiguous csr_col (u16) window.
__global__ __launch_bounds__(256) void finalize_csr(const unsigned* __restrict__ edge_buf,
                                                    const int* __restrict__ bucket_cnt,
                                                    const int* __restrict__ bucket_base,
                                                    int* __restrict__ rowptr,
                                                    float* __restrict__ invdeg,
                                                    unsigned short* __restrict__ csr_col) {
    __shared__ int hist[256], excl[256], cur[256], scan[256];
    int b = blockIdx.x;
    int tid = threadIdx.x;
    int cnt = bucket_cnt[b];
    int base = bucket_base[b];
    const unsigned* src = edge_buf + (size_t)b * BUK_CAP;
    hist[tid] = 0; cur[tid] = 0;
    __syncthreads();
    for (int i = tid; i < cnt; i += 256)
        atomicAdd(&hist[(src[i] >> 16) & 255], 1);
    __syncthreads();
    scan[tid] = hist[tid];
    __syncthreads();
    for (int off = 1; off < 256; off <<= 1) {
        int v = (tid >= off) ? scan[tid - off] : 0;
        __syncthreads();
        scan[tid] += v;
        __syncthreads();
    }
    excl[tid] = (tid == 0) ? 0 : scan[tid - 1];
    __syncthreads();
    int r = b * 256 + tid;
    if (r < N_NODES) {
        rowptr[r] = base + excl[tid];
        invdeg[r] = 1.0f / (float)(hist[tid] + 1);   // +1: self loop
    }
    if (b == NBUK - 1 && tid == 0) rowptr[N_NODES] = base + cnt;
    for (int i = tid; i < cnt; i += 256) {
        unsigned rec = src[i];
        int rl = (rec >> 16) & 255;
        int pos = excl[rl] + atomicAdd(&cur[rl], 1);
        csr_col[base + pos] = (unsigned short)(rec & 0xFFFFu);
    }
}

// ---------------------------------------------------------------- converts

// x f32 [N][128] -> chunked packed bf16x2: xb[chunk(4)][node][16 u32]
__global__ __launch_bounds__(256) void convert_x(const float* __restrict__ x,
                                                 unsigned* __restrict__ xb) {
    int i = blockIdx.x * 256 + threadIdx.x;   // over N*64 pairs
    if (i < N_NODES * 64) {
        int n = i >> 6, pp = i & 63;
        int c = pp >> 4, pl = pp & 15;
        float2 v = ((const float2*)x)[i];
        xb[((size_t)c * N_NODES + n) * CHUNK_U + pl] =
            (unsigned)f2bf(v.x) | ((unsigned)f2bf(v.y) << 16);
    }
}

// w1 f32 [128][512] -> bf16 pre-swizzled to MFMA B-frag order: [t(32)][s(4)][lane(64)][j(8)]
__global__ __launch_bounds__(256) void make_w1p(const float* __restrict__ w1,
                                                unsigned short* __restrict__ w1p) {
    int i = blockIdx.x * 256 + threadIdx.x;     // 65536 total
    int j = i & 7, lane = (i >> 3) & 63, s = (i >> 9) & 3, t = i >> 11;
    int k = s * 32 + (lane >> 4) * 8 + j;
    int n = t * 16 + (lane & 15);
    w1p[i] = f2bf(w1[(size_t)k * D_H + n]);
}

// fold the post-pool linear layers: wcomb = w2 @ wc (512x16), bcomb = b2 @ wc + bc (16).
__global__ __launch_bounds__(256) void fold_w(const float* __restrict__ w2,
                                              const float* __restrict__ wc,
                                              const float* __restrict__ b2,
                                              const float* __restrict__ bc,
                                              float* __restrict__ wcomb,
                                              float* __restrict__ bcomb) {
    int tid = threadIdx.x;
    int o = tid & 15, kl = tid >> 4;
    int k = blockIdx.x * 16 + kl;
    if (k > D_H) return;
    const float* wr = (k < D_H) ? (w2 + (size_t)k * D_H) : b2;
    float s = 0.f;
    for (int j = 0; j < D_H; j += 4) {
        s += wr[j + 0] * wc[(j + 0) * D_OUT + o]
           + wr[j + 1] * wc[(j + 1) * D_OUT + o]
           + wr[j + 2] * wc[(j + 2) * D_OUT + o]
           + wr[j + 3] * wc[(j + 3) * D_OUT + o];
    }
    if (k < D_H) wcomb[k * D_OUT + o] = s;
    else         bcomb[o] = s + bc[o];
}

// ---------------------------------------------------------------- propagation (bf16, feature-chunked)
// One ROW per WAVE (uniform trip count, zero divergence); the wave's 4 lane-quads
// process 4 edges simultaneously (quad = edge, l = feature). One gather instruction
// = 4 edges x 64 B = 4 lines (1 line/edge vs 4 in the 256B layout). Quad partial
// accumulators reduced by shfl_xor at the end. csr_col (u16) is nontemporal-read,
// xout nontemporal-written -> L2 keeps only the 3.2 MB xin chunk.

__global__ __launch_bounds__(256) void propagate_chunk(const unsigned* __restrict__ xin,
                                                       unsigned* __restrict__ xout,
                                                       const int* __restrict__ rowptr,
                                                       const unsigned short* __restrict__ csr_col,
                                                       const float* __restrict__ invdeg) {
    int t = threadIdx.x;
    int lane = t & 63;
    int wave = t >> 6;
    int quad = lane >> 4;              // which of 4 concurrent edges
    int l = lane & 15;                 // feature slot (16 u32 = 64 B)
    const unsigned* xc = xin + (size_t)blockIdx.y * ((size_t)N_NODES * CHUNK_U);
    unsigned*       oc = xout + (size_t)blockIdx.y * ((size_t)N_NODES * CHUNK_U);
    int r = blockIdx.x * 4 + wave;
    if (r >= N_NODES) return;
    int beg = rowptr[r], end = rowptr[r + 1];
    unsigned su = xc[(size_t)r * CHUNK_U + l];     // self loop (same line for all quads)
    float acc0 = (quad == 0) ? __uint_as_float(su << 16) : 0.f;
    float acc1 = (quad == 0) ? __uint_as_float(su & 0xffff0000u) : 0.f;
    for (int cs = beg; cs < end; cs += 64) {
        int nn = end - cs; if (nn > 64) nn = 64;
        int colv = (int)__builtin_nontemporal_load(&csr_col[cs + (lane < nn ? lane : 0)]);
        int j = 0;
        for (; j + 16 <= nn; j += 16) {            // 4 independent 4-edge gathers in flight
            int cA = __shfl(colv, j + 0 + quad, 64);
            int cB = __shfl(colv, j + 4 + quad, 64);
            int cC = __shfl(colv, j + 8 + quad, 64);
            int cD = __shfl(colv, j + 12 + quad, 64);
            unsigned uA = xc[(size_t)cA * CHUNK_U + l];
            unsigned uB = xc[(size_t)cB * CHUNK_U + l];
            unsigned uC = xc[(size_t)cC * CHUNK_U + l];
            unsigned uD = xc[(size_t)cD * CHUNK_U + l];
            acc0 += __uint_as_float(uA << 16) + __uint_as_float(uB << 16)
                  + __uint_as_float(uC << 16) + __uint_as_float(uD << 16);
            acc1 += __uint_as_float(uA & 0xffff0000u) + __uint_as_float(uB & 0xffff0000u)
                  + __uint_as_float(uC & 0xffff0000u) + __uint_as_float(uD & 0xffff0000u);
        }
        for (; j < nn; j += 4) {                   // predicated 4-edge tail (wave-uniform)
            int e = j + quad;
            int c = __shfl(colv, e < nn ? e : 0, 64);
            unsigned u = xc[(size_t)c * CHUNK_U + l];
            if (e >= nn) u = 0u;
            acc0 += __uint_as_float(u << 16);
            acc1 += __uint_as_float(u & 0xffff0000u);
        }
    }
    // reduce the 4 quad partials (feature l aligns across quads)
    acc0 += __shfl_xor(acc0, 16, 64);
    acc0 += __shfl_xor(acc0, 32, 64);
    acc1 += __shfl_xor(acc1, 16, 64);
    acc1 += __shfl_xor(acc1, 32, 64);
    float inv = invdeg[r];
    if (quad == 0) {
        unsigned pv = (unsigned)f2bf(acc0 * inv) | ((unsigned)f2bf(acc1 * inv) << 16);
        __builtin_nontemporal_store(pv, &oc[(size_t)r * CHUNK_U + l]);
    }
}

// ---------------------------------------------------------------- MFMA GEMM (h3 @ w1) + bias + ReLU + segmented pool
// h3 in chunked layout: chunk s holds exactly K-step s's features -> 16B frag load.

__global__ __launch_bounds__(256) void gemm_mfma_pool(const unsigned* __restrict__ h3u,
                                                      const unsigned short* __restrict__ w1p,
                                                      const float* __restrict__ b1,
                                                      const int* __restrict__ batch,
                                                      float* __restrict__ gsum) {
    __shared__ float hls[64][132];   // +4 pad: conflict-free row-strided writes
    __shared__ int bls[64];
    int tid = threadIdx.x;
    int lane = tid & 63, wave = tid >> 6;
    int quad = lane >> 4, l15 = lane & 15;
    int mbase = blockIdx.x * 64;
    int nbase = blockIdx.y * 128;

    int m = mbase + wave * 16 + l15;
    int mc = m < N_NODES ? m : N_NODES - 1;          // clamp; garbage rows skipped in epilogue
    bf16x8 afrag[4];
#pragma unroll
    for (int s = 0; s < 4; ++s)
        afrag[s] = *(const bf16x8*)(h3u + ((size_t)s * N_NODES + mc) * CHUNK_U + quad * 4);

    f32x4 acc[8];
#pragma unroll
    for (int t = 0; t < 8; ++t) acc[t] = (f32x4){0.f, 0.f, 0.f, 0.f};

    const unsigned short* bbase = w1p + ((size_t)(blockIdx.y * 8) * 4 * 64 + lane) * 8;
#pragma unroll
    for (int t = 0; t < 8; ++t) {
#pragma unroll
        for (int s = 0; s < 4; ++s) {
            bf16x8 bfrag = *(const bf16x8*)(bbase + (size_t)(t * 4 + s) * 64 * 8);
            acc[t] = __builtin_amdgcn_mfma_f32_16x16x32_bf16(afrag[s], bfrag, acc[t], 0, 0, 0);
        }
    }

    if (tid < 64) {
        int mm = mbase + tid;
        bls[tid] = (mm < N_NODES) ? batch[mm] : 0;
    }
#pragma unroll
    for (int t = 0; t < 8; ++t)
#pragma unroll
        for (int rg = 0; rg < 4; ++rg)
            hls[wave * 16 + quad * 4 + rg][t * 16 + l15] = acc[t][rg];
    __syncthreads();

    // epilogue: bias + relu + sorted-segment pool; thread owns (col, 32-row half)
    int c = tid & 127, half = tid >> 7;
    float bias = b1[nbase + c];
    int r0 = half * 32;
    int cur = bls[r0];
    float s = 0.f;
    for (int r = r0; r < r0 + 32; ++r) {
        int mm = mbase + r;
        if (mm >= N_NODES) break;
        int g = bls[r];
        float v = hls[r][c] + bias;
        v = v > 0.f ? v : 0.f;
        if (g != cur) { atomicAdd(&gsum[cur * D_H + nbase + c], s); s = 0.f; cur = g; }
        s += v;
    }
    atomicAdd(&gsum[cur * D_H + nbase + c], s);
}

// ---------------------------------------------------------------- final: mean + folded (512x16) projection

__global__ __launch_bounds__(256) void final_pool(const float* __restrict__ gsum,
                                                  const int* __restrict__ gcnt,
                                                  const float* __restrict__ wcomb,
                                                  const float* __restrict__ bcomb,
                                                  float* __restrict__ out) {
    int g = blockIdx.x;
    int tid = threadIdx.x;
    __shared__ float p[D_H];
    __shared__ float part[16][17];
    int c = gcnt[g]; if (c < 1) c = 1;
    float inv = 1.0f / (float)c;
    p[tid] = gsum[g * D_H + tid] * inv;
    p[tid + 256] = gsum[g * D_H + tid + 256] * inv;
    __syncthreads();
    int o = tid & 15, ch = tid >> 4;
    int k0 = ch * 32;
    float s = 0.f;
    for (int k = k0; k < k0 + 32; ++k)
        s += p[k] * wcomb[k * D_OUT + o];
    part[ch][o] = s;
    __syncthreads();
    if (tid < D_OUT) {
        float t = bcomb[tid];
        for (int ch2 = 0; ch2 < 16; ++ch2) t += part[ch2][tid];
        out[g * D_OUT + tid] = t;
    }
}

// ---------------------------------------------------------------- launch

extern "C" void kernel_launch(void* const* d_in, const int* in_sizes, int n_in,
                              void* d_out, int out_size, void* d_ws, size_t ws_size,
                              hipStream_t stream) {
    const float* x     = (const float*)d_in[0];
    const int*   eidx  = (const int*)d_in[1];   // [2, E]
    const int*   batch = (const int*)d_in[2];
    const float* w1    = (const float*)d_in[3];
    const float* b1    = (const float*)d_in[4];
    const float* w2    = (const float*)d_in[5];
    const float* b2    = (const float*)d_in[6];
    const float* wc    = (const float*)d_in[7];
    const float* bc    = (const float*)d_in[8];
    float* out = (float*)d_out;
    const int* row = eidx;
    const int* col = eidx + N_EDGES;

    char* p = (char*)d_ws;
    auto alloc = [&](size_t bytes) { char* q = p; p += (bytes + 255) & ~(size_t)255; return q; };
    // zero-init region: bucket_cnt, gsum contiguous -> ONE memset
    char* zbase = p;
    int*   bucket_cnt = (int*)alloc((size_t)NBUK * 4);
    float* gsum       = (float*)alloc((size_t)N_GRAPHS * D_H * 4);
    size_t zbytes = (size_t)(p - zbase);
    int*   bucket_base = (int*)alloc((size_t)NBUK * 4);
    int*   rowptr  = (int*)alloc((size_t)(N_NODES + 1) * 4);
    int*   gcnt    = (int*)alloc((size_t)N_GRAPHS * 4);
    float* invdeg  = (float*)alloc((size_t)N_NODES * 4);
    float* wcomb   = (float*)alloc((size_t)D_H * D_OUT * 4);
    float* bcomb   = (float*)alloc((size_t)D_OUT * 4);
    unsigned* edge_buf = (unsigned*)alloc((size_t)NBUK * BUK_CAP * 4);
    unsigned short* csr_col = (unsigned short*)alloc((size_t)N_EDGES * 2);
    unsigned* xb   = (unsigned*)alloc((size_t)N_NODES * 64 * 4);   // chunked bf16x2
    unsigned* h0b  = (unsigned*)alloc((size_t)N_NODES * 64 * 4);
    unsigned* h1b  = (unsigned*)alloc((size_t)N_NODES * 64 * 4);
    unsigned short* w1p = (unsigned short*)alloc((size_t)D_IN * D_H * 2);

    (void)hipMemsetAsync(zbase, 0, zbytes, stream);

    convert_x<<<(N_NODES * 64 + 255) / 256, 256, 0, stream>>>(x, xb);
    make_w1p<<<(D_IN * D_H) / 256, 256, 0, stream>>>(w1, w1p);
    fold_w<<<33, 256, 0, stream>>>(w2, wc, b2, bc, wcomb, bcomb);
    graph_counts<<<1, 64, 0, stream>>>(batch, gcnt);

    partition_edges<<<P1_BLOCKS, 256, 0, stream>>>(row, col, bucket_cnt, edge_buf);
    scan_buckets<<<1, 256, 0, stream>>>(bucket_cnt, bucket_base);
    finalize_csr<<<NBUK, 256, 0, stream>>>(edge_buf, bucket_cnt, bucket_base,
                                           rowptr, invdeg, csr_col);

    dim3 pgrid((N_NODES + 3) / 4, NCHUNK);
    propagate_chunk<<<pgrid, 256, 0, stream>>>(xb,  h0b, rowptr, csr_col, invdeg);
    propagate_chunk<<<pgrid, 256, 0, stream>>>(h0b, h1b, rowptr, csr_col, invdeg);
    propagate_chunk<<<pgrid, 256, 0, stream>>>(h1b, h0b, rowptr, csr_col, invdeg);

    dim3 ggrid((N_NODES + 63) / 64, D_H / 128);
    gemm_mfma_pool<<<ggrid, 256, 0, stream>>>(h0b, w1p, b1, batch, gsum);
    final_pool<<<N_GRAPHS, 256, 0, stream>>>(gsum, gcnt, wcomb, bcomb, out);
}

// Round 11
// 338.092 us; speedup vs baseline: 1.3484x; 1.3484x over previous
//
#include <hip/hip_runtime.h>
#include <hip/hip_bf16.h>

#define N_NODES 50000
#define N_EDGES 1600000
#define N_GRAPHS 64
#define D_IN 128
#define D_H 512
#define D_OUT 16

// atomic-free CSR build: buckets of 256 rows
#define NBUK 196                      // ceil(50000/256)
#define BUK_CAP 9216                  // per-bucket capacity: mean 8192 + ~11 sigma
#define P1_EDGES 8192                 // edges per partition block
#define P1_BLOCKS ((N_EDGES + P1_EDGES - 1) / P1_EDGES)   // 196

typedef short bf16x8 __attribute__((ext_vector_type(8)));
typedef float f32x4 __attribute__((ext_vector_type(4)));

static __device__ __forceinline__ unsigned short f2bf(float f) {
    __hip_bfloat16 h = __float2bfloat16(f);   // RNE
    return *(unsigned short*)&h;
}

// batch is SORTED: gcnt[g] = lower_bound(g+1) - lower_bound(g). 64 threads, no atomics.
__global__ __launch_bounds__(64) void graph_counts(const int* __restrict__ batch,
                                                   int* __restrict__ gcnt) {
    int g = threadIdx.x;
    int lo = 0, hi = N_NODES;
    while (lo < hi) { int mid = (lo + hi) >> 1; if (batch[mid] < g) lo = mid + 1; else hi = mid; }
    int a = lo;
    lo = 0; hi = N_NODES;
    while (lo < hi) { int mid = (lo + hi) >> 1; if (batch[mid] < g + 1) lo = mid + 1; else hi = mid; }
    gcnt[g] = lo - a;
}

// ---------------------------------------------------------------- CSR build (atomic-free)

__global__ __launch_bounds__(256) void partition_edges(const int* __restrict__ row,
                                                       const int* __restrict__ col,
                                                       int* __restrict__ bucket_cnt,
                                                       unsigned* __restrict__ edge_buf) {
    __shared__ unsigned recs[P1_EDGES];     // 32 KB
    __shared__ unsigned sorted[P1_EDGES];   // 32 KB
    __shared__ int hist[NBUK];              // counts, then repurposed as local excl base
    __shared__ int cur[NBUK];
    __shared__ int gbase[NBUK];
    __shared__ int scan[256];
    int tid = threadIdx.x;
    int e0 = blockIdx.x * P1_EDGES;
    int m = N_EDGES - e0; if (m > P1_EDGES) m = P1_EDGES;

    for (int i = tid; i < NBUK; i += 256) { hist[i] = 0; cur[i] = 0; }
    __syncthreads();
    for (int i = tid; i < m; i += 256) {
        int r = row[e0 + i];
        int c = col[e0 + i];
        int buk = r >> 8;
        recs[i] = ((unsigned)buk << 24) | ((unsigned)(r & 255) << 16) | (unsigned)c;
        atomicAdd(&hist[buk], 1);
    }
    __syncthreads();
    scan[tid] = (tid < NBUK) ? hist[tid] : 0;
    __syncthreads();
    for (int off = 1; off < 256; off <<= 1) {
        int v = (tid >= off) ? scan[tid - off] : 0;
        __syncthreads();
        scan[tid] += v;
        __syncthreads();
    }
    if (tid < NBUK) {
        int cnt = hist[tid];
        hist[tid] = (tid == 0) ? 0 : scan[tid - 1];            // local excl base
        gbase[tid] = (cnt > 0) ? atomicAdd(&bucket_cnt[tid], cnt) : 0;  // reserve range
    }
    __syncthreads();
    for (int i = tid; i < m; i += 256) {                       // rank + reorder (bucket-major)
        unsigned rec = recs[i];
        int buk = rec >> 24;
        int rank = atomicAdd(&cur[buk], 1);
        sorted[hist[buk] + rank] = rec;
    }
    __syncthreads();
    for (int p = tid; p < m; p += 256) {                       // coalesced-run writes
        unsigned rec = sorted[p];
        int buk = rec >> 24;
        edge_buf[(size_t)buk * BUK_CAP + gbase[buk] + (p - hist[buk])] = rec;
    }
}

__global__ __launch_bounds__(256) void scan_buckets(const int* __restrict__ bucket_cnt,
                                                    int* __restrict__ bucket_base) {
    __shared__ int scan[256];
    int tid = threadIdx.x;
    scan[tid] = (tid < NBUK) ? bucket_cnt[tid] : 0;
    __syncthreads();
    for (int off = 1; off < 256; off <<= 1) {
        int v = (tid >= off) ? scan[tid - off] : 0;
        __syncthreads();
        scan[tid] += v;
        __syncthreads();
    }
    if (tid < NBUK) bucket_base[tid] = (tid == 0) ? 0 : scan[tid - 1];
}

// P2: one block per bucket. LDS hist+scan -> rowptr/invdeg; LDS-cursor scatter into the
// bucket's contiguous csr_col (u16) window.
__global__ __launch_bounds__(256) void finalize_csr(const unsigned* __restrict__ edge_buf,
                                                    const int* __restrict__ bucket_cnt,
                                                    const int* __restrict__ bucket_base,
                                                    int* __restrict__ rowptr,
                                                    float* __restrict__ invdeg,
                                                    unsigned short* __restrict__ csr_col) {
    __shared__ int hist[256], excl[256], cur[256], scan[256];
    int b = blockIdx.x;
    int tid = threadIdx.x;
    int cnt = bucket_cnt[b];
    int base = bucket_base[b];
    const unsigned* src = edge_buf + (size_t)b * BUK_CAP;
    hist[tid] = 0; cur[tid] = 0;
    __syncthreads();
    for (int i = tid; i < cnt; i += 256)
        atomicAdd(&hist[(src[i] >> 16) & 255], 1);
    __syncthreads();
    scan[tid] = hist[tid];
    __syncthreads();
    for (int off = 1; off < 256; off <<= 1) {
        int v = (tid >= off) ? scan[tid - off] : 0;
        __syncthreads();
        scan[tid] += v;
        __syncthreads();
    }
    excl[tid] = (tid == 0) ? 0 : scan[tid - 1];
    __syncthreads();
    int r = b * 256 + tid;
    if (r < N_NODES) {
        rowptr[r] = base + excl[tid];
        invdeg[r] = 1.0f / (float)(hist[tid] + 1);   // +1: self loop
    }
    if (b == NBUK - 1 && tid == 0) rowptr[N_NODES] = base + cnt;
    for (int i = tid; i < cnt; i += 256) {
        unsigned rec = src[i];
        int rl = (rec >> 16) & 255;
        int pos = excl[rl] + atomicAdd(&cur[rl], 1);
        csr_col[base + pos] = (unsigned short)(rec & 0xFFFFu);
    }
}

// ---------------------------------------------------------------- converts

// x f32 [N][128] -> packed bf16x2 [N][64]  (node-major, R8 layout)
__global__ __launch_bounds__(256) void convert_x(const float* __restrict__ x,
                                                 unsigned* __restrict__ xb, int npairs) {
    int i = blockIdx.x * 256 + threadIdx.x;
    if (i < npairs) {
        float2 v = ((const float2*)x)[i];
        xb[i] = (unsigned)f2bf(v.x) | ((unsigned)f2bf(v.y) << 16);
    }
}

// w1 f32 [128][512] -> bf16 pre-swizzled to MFMA B-frag order: [t(32)][s(4)][lane(64)][j(8)]
__global__ __launch_bounds__(256) void make_w1p(const float* __restrict__ w1,
                                                unsigned short* __restrict__ w1p) {
    int i = blockIdx.x * 256 + threadIdx.x;     // 65536 total
    int j = i & 7, lane = (i >> 3) & 63, s = (i >> 9) & 3, t = i >> 11;
    int k = s * 32 + (lane >> 4) * 8 + j;
    int n = t * 16 + (lane & 15);
    w1p[i] = f2bf(w1[(size_t)k * D_H + n]);
}

// fold the post-pool linear layers: wcomb = w2 @ wc (512x16), bcomb = b2 @ wc + bc (16).
__global__ __launch_bounds__(256) void fold_w(const float* __restrict__ w2,
                                              const float* __restrict__ wc,
                                              const float* __restrict__ b2,
                                              const float* __restrict__ bc,
                                              float* __restrict__ wcomb,
                                              float* __restrict__ bcomb) {
    int tid = threadIdx.x;
    int o = tid & 15, kl = tid >> 4;
    int k = blockIdx.x * 16 + kl;
    if (k > D_H) return;
    const float* wr = (k < D_H) ? (w2 + (size_t)k * D_H) : b2;
    float s = 0.f;
    for (int j = 0; j < D_H; j += 4) {
        s += wr[j + 0] * wc[(j + 0) * D_OUT + o]
           + wr[j + 1] * wc[(j + 1) * D_OUT + o]
           + wr[j + 2] * wc[(j + 2) * D_OUT + o]
           + wr[j + 3] * wc[(j + 3) * D_OUT + o];
    }
    if (k < D_H) wcomb[k * D_OUT + o] = s;
    else         bcomb[o] = s + bc[o];
}

// ---------------------------------------------------------------- propagation (bf16 storage, f32 accumulate)
// R8 execution shape (best measured): one row per wave, contiguous 256B row gathers,
// col indices shfl-broadcast from lane regs, no LDS/barriers. Tweaks vs R8:
// u16 csr_col (half the index stream) and 16 gathers in flight in the main loop
// (deg~33 -> 2 latency-exposed phases per row instead of 4).

__global__ __launch_bounds__(256) void propagate_bf16(const unsigned* __restrict__ xin,
                                                      unsigned* __restrict__ xout,
                                                      const int* __restrict__ rowptr,
                                                      const unsigned short* __restrict__ csr_col,
                                                      const float* __restrict__ invdeg) {
    int wave = threadIdx.x >> 6;
    int lane = threadIdx.x & 63;
    int r = blockIdx.x * 4 + wave;
    if (r >= N_NODES) return;
    int beg = rowptr[r], end = rowptr[r + 1];
    unsigned u = xin[(size_t)r * 64 + lane];      // self loop
    float acc0 = __uint_as_float(u << 16);
    float acc1 = __uint_as_float(u & 0xffff0000u);
    for (int cs = beg; cs < end; cs += 64) {
        int nn = end - cs; if (nn > 64) nn = 64;
        int colv = (int)csr_col[cs + (lane < nn ? lane : 0)];
        int j = 0;
        for (; j + 16 <= nn; j += 16) {           // 16 independent 256B gathers in flight
            unsigned uu[16];
#pragma unroll
            for (int q = 0; q < 16; ++q) {
                int c = __shfl(colv, j + q, 64);
                uu[q] = xin[(size_t)c * 64 + lane];
            }
#pragma unroll
            for (int q = 0; q < 16; ++q) {
                acc0 += __uint_as_float(uu[q] << 16);
                acc1 += __uint_as_float(uu[q] & 0xffff0000u);
            }
        }
        for (; j + 4 <= nn; j += 4) {
            int c0 = __shfl(colv, j + 0, 64), c1 = __shfl(colv, j + 1, 64);
            int c2 = __shfl(colv, j + 2, 64), c3 = __shfl(colv, j + 3, 64);
            unsigned u0 = xin[(size_t)c0 * 64 + lane];
            unsigned u1 = xin[(size_t)c1 * 64 + lane];
            unsigned u2 = xin[(size_t)c2 * 64 + lane];
            unsigned u3 = xin[(size_t)c3 * 64 + lane];
            acc0 += __uint_as_float(u0 << 16) + __uint_as_float(u1 << 16)
                  + __uint_as_float(u2 << 16) + __uint_as_float(u3 << 16);
            acc1 += __uint_as_float(u0 & 0xffff0000u) + __uint_as_float(u1 & 0xffff0000u)
                  + __uint_as_float(u2 & 0xffff0000u) + __uint_as_float(u3 & 0xffff0000u);
        }
        for (; j < nn; ++j) {
            int c = __shfl(colv, j, 64);
            unsigned uu = xin[(size_t)c * 64 + lane];
            acc0 += __uint_as_float(uu << 16);
            acc1 += __uint_as_float(uu & 0xffff0000u);
        }
    }
    float inv = invdeg[r];
    acc0 *= inv; acc1 *= inv;
    xout[(size_t)r * 64 + lane] = (unsigned)f2bf(acc0) | ((unsigned)f2bf(acc1) << 16);
}

// ---------------------------------------------------------------- MFMA GEMM (h3 @ w1) + bias + ReLU + segmented pool
// block 256 = 4 waves; tile M=64, N=128; K=128 (4 steps of 32). R8 form (node-major h3).

__global__ __launch_bounds__(256) void gemm_mfma_pool(const unsigned short* __restrict__ h3b,
                                                      const unsigned short* __restrict__ w1p,
                                                      const float* __restrict__ b1,
                                                      const int* __restrict__ batch,
                                                      float* __restrict__ gsum) {
    __shared__ float hls[64][132];   // +4 pad: conflict-free row-strided writes
    __shared__ int bls[64];
    int tid = threadIdx.x;
    int lane = tid & 63, wave = tid >> 6;
    int quad = lane >> 4, l15 = lane & 15;
    int mbase = blockIdx.x * 64;
    int nbase = blockIdx.y * 128;

    int m = mbase + wave * 16 + l15;
    int mc = m < N_NODES ? m : N_NODES - 1;          // clamp; garbage rows skipped in epilogue
    const unsigned short* arow = h3b + (size_t)mc * 128 + quad * 8;
    bf16x8 afrag[4];
#pragma unroll
    for (int s = 0; s < 4; ++s)
        afrag[s] = *(const bf16x8*)(arow + s * 32);

    f32x4 acc[8];
#pragma unroll
    for (int t = 0; t < 8; ++t) acc[t] = (f32x4){0.f, 0.f, 0.f, 0.f};

    const unsigned short* bbase = w1p + ((size_t)(blockIdx.y * 8) * 4 * 64 + lane) * 8;
#pragma unroll
    for (int t = 0; t < 8; ++t) {
#pragma unroll
        for (int s = 0; s < 4; ++s) {
            bf16x8 bfrag = *(const bf16x8*)(bbase + (size_t)(t * 4 + s) * 64 * 8);
            acc[t] = __builtin_amdgcn_mfma_f32_16x16x32_bf16(afrag[s], bfrag, acc[t], 0, 0, 0);
        }
    }

    if (tid < 64) {
        int mm = mbase + tid;
        bls[tid] = (mm < N_NODES) ? batch[mm] : 0;
    }
#pragma unroll
    for (int t = 0; t < 8; ++t)
#pragma unroll
        for (int rg = 0; rg < 4; ++rg)
            hls[wave * 16 + quad * 4 + rg][t * 16 + l15] = acc[t][rg];
    __syncthreads();

    // epilogue: bias + relu + sorted-segment pool; thread owns (col, 32-row half)
    int c = tid & 127, half = tid >> 7;
    float bias = b1[nbase + c];
    int r0 = half * 32;
    int cur = bls[r0];
    float s = 0.f;
    for (int r = r0; r < r0 + 32; ++r) {
        int mm = mbase + r;
        if (mm >= N_NODES) break;
        int g = bls[r];
        float v = hls[r][c] + bias;
        v = v > 0.f ? v : 0.f;
        if (g != cur) { atomicAdd(&gsum[cur * D_H + nbase + c], s); s = 0.f; cur = g; }
        s += v;
    }
    atomicAdd(&gsum[cur * D_H + nbase + c], s);
}

// ---------------------------------------------------------------- final: mean + folded (512x16) projection

__global__ __launch_bounds__(256) void final_pool(const float* __restrict__ gsum,
                                                  const int* __restrict__ gcnt,
                                                  const float* __restrict__ wcomb,
                                                  const float* __restrict__ bcomb,
                                                  float* __restrict__ out) {
    int g = blockIdx.x;
    int tid = threadIdx.x;
    __shared__ float p[D_H];
    __shared__ float part[16][17];
    int c = gcnt[g]; if (c < 1) c = 1;
    float inv = 1.0f / (float)c;
    p[tid] = gsum[g * D_H + tid] * inv;
    p[tid + 256] = gsum[g * D_H + tid + 256] * inv;
    __syncthreads();
    int o = tid & 15, ch = tid >> 4;
    int k0 = ch * 32;
    float s = 0.f;
    for (int k = k0; k < k0 + 32; ++k)
        s += p[k] * wcomb[k * D_OUT + o];
    part[ch][o] = s;
    __syncthreads();
    if (tid < D_OUT) {
        float t = bcomb[tid];
        for (int ch2 = 0; ch2 < 16; ++ch2) t += part[ch2][tid];
        out[g * D_OUT + tid] = t;
    }
}

// ---------------------------------------------------------------- launch

extern "C" void kernel_launch(void* const* d_in, const int* in_sizes, int n_in,
                              void* d_out, int out_size, void* d_ws, size_t ws_size,
                              hipStream_t stream) {
    const float* x     = (const float*)d_in[0];
    const int*   eidx  = (const int*)d_in[1];   // [2, E]
    const int*   batch = (const int*)d_in[2];
    const float* w1    = (const float*)d_in[3];
    const float* b1    = (const float*)d_in[4];
    const float* w2    = (const float*)d_in[5];
    const float* b2    = (const float*)d_in[6];
    const float* wc    = (const float*)d_in[7];
    const float* bc    = (const float*)d_in[8];
    float* out = (float*)d_out;
    const int* row = eidx;
    const int* col = eidx + N_EDGES;

    char* p = (char*)d_ws;
    auto alloc = [&](size_t bytes) { char* q = p; p += (bytes + 255) & ~(size_t)255; return q; };
    // zero-init region: bucket_cnt, gsum contiguous -> ONE memset
    char* zbase = p;
    int*   bucket_cnt = (int*)alloc((size_t)NBUK * 4);
    float* gsum       = (float*)alloc((size_t)N_GRAPHS * D_H * 4);
    size_t zbytes = (size_t)(p - zbase);
    int*   bucket_base = (int*)alloc((size_t)NBUK * 4);
    int*   rowptr  = (int*)alloc((size_t)(N_NODES + 1) * 4);
    int*   gcnt    = (int*)alloc((size_t)N_GRAPHS * 4);
    float* invdeg  = (float*)alloc((size_t)N_NODES * 4);
    float* wcomb   = (float*)alloc((size_t)D_H * D_OUT * 4);
    float* bcomb   = (float*)alloc((size_t)D_OUT * 4);
    unsigned* edge_buf = (unsigned*)alloc((size_t)NBUK * BUK_CAP * 4);
    unsigned short* csr_col = (unsigned short*)alloc((size_t)N_EDGES * 2);
    unsigned* xb   = (unsigned*)alloc((size_t)N_NODES * 64 * 4);   // bf16x2 packed, node-major
    unsigned* h0b  = (unsigned*)alloc((size_t)N_NODES * 64 * 4);
    unsigned* h1b  = (unsigned*)alloc((size_t)N_NODES * 64 * 4);
    unsigned short* w1p = (unsigned short*)alloc((size_t)D_IN * D_H * 2);

    (void)hipMemsetAsync(zbase, 0, zbytes, stream);

    convert_x<<<(N_NODES * 64 + 255) / 256, 256, 0, stream>>>(x, xb, N_NODES * 64);
    make_w1p<<<(D_IN * D_H) / 256, 256, 0, stream>>>(w1, w1p);
    fold_w<<<33, 256, 0, stream>>>(w2, wc, b2, bc, wcomb, bcomb);
    graph_counts<<<1, 64, 0, stream>>>(batch, gcnt);

    partition_edges<<<P1_BLOCKS, 256, 0, stream>>>(row, col, bucket_cnt, edge_buf);
    scan_buckets<<<1, 256, 0, stream>>>(bucket_cnt, bucket_base);
    finalize_csr<<<NBUK, 256, 0, stream>>>(edge_buf, bucket_cnt, bucket_base,
                                           rowptr, invdeg, csr_col);

    propagate_bf16<<<(N_NODES + 3) / 4, 256, 0, stream>>>(xb,  h0b, rowptr, csr_col, invdeg);
    propagate_bf16<<<(N_NODES + 3) / 4, 256, 0, stream>>>(h0b, h1b, rowptr, csr_col, invdeg);
    propagate_bf16<<<(N_NODES + 3) / 4, 256, 0, stream>>>(h1b, h0b, rowptr, csr_col, invdeg);

    dim3 ggrid((N_NODES + 63) / 64, D_H / 128);
    gemm_mfma_pool<<<ggrid, 256, 0, stream>>>((const unsigned short*)h0b, w1p, b1, batch, gsum);
    final_pool<<<N_GRAPHS, 256, 0, stream>>>(gsum, gcnt, wcomb, bcomb, out);
}